// Round 14
// baseline (179.370 us; speedup 1.0000x reference)
//
#include <hip/hip_runtime.h>
#include <hip/hip_bf16.h>

// MultiHeadAttention: B=4, T=2048, DIM=64, H=12. fp32 I/O.
// Flat-reshape semantics: QKV are (8192,768) row-major; attention slices are
// contiguous 131072-elem chunks. Roles: queries = K rows (i), keys = Q rows
// (j), values = V rows, softmax over j.
// Round 22: decomposition: gaps ~3us (r12 vs r13); qkv ~= 65-70us and is
// latency-CHAIN bound (insensitive to occupancy and store format): per cc,
// 8 L2 loads -> 8 dependent MFMAs -> stores, serialized 6x. Fix: register
// prefetch double-buffer (issue cc+1's B-frag loads before cc's MFMAs) —
// the same reg-prefetch pattern that fixed attn. attn = r13 core + XCD
// swizzle ONLY (r13's FETCH 104->20MB proved the mapping; chain-break caused
// the +6.5us regression and is reverted). prep/vtrans/out = r6 verbatim.

#define DIM 64
#define NH 12
#define HD 768
#define BT 8192
#define TSEQ 2048
#define NSLICE 48
#define SLICE (TSEQ*DIM)

#define LDQ 72   // LDS row strides (ushorts)
#define LDT 72

typedef unsigned short ushort;
typedef __attribute__((ext_vector_type(8))) short bf16x8;
typedef __attribute__((ext_vector_type(4))) short bf16x4;
typedef __attribute__((ext_vector_type(4))) float f32x4;
typedef __attribute__((ext_vector_type(16))) float f32x16;
typedef __attribute__((ext_vector_type(4))) unsigned int uint32x4;

#define SCALE2 0.18033688011112042f   // 0.125 * log2(e)

__device__ __forceinline__ ushort f2b(float f) {
    union { float f; unsigned int i; } v; v.f = f;
    unsigned int x = v.i;
    return (ushort)((x + 0x7fffu + ((x >> 16) & 1u)) >> 16);  // RNE
}

// ---------------- prep: transpose + convert weights ------------------------
// 48 blocks: z = bx/12 (Wq,Wk,Wv,Wo), tile = bx%12.
__global__ __launch_bounds__(256) void prep_w(
    const float* __restrict__ Wq, const float* __restrict__ Wk,
    const float* __restrict__ Wv, const float* __restrict__ Wo,
    ushort* __restrict__ Wt, ushort* __restrict__ Wot)
{
    __shared__ float tile[64][65];
    int bx = blockIdx.x;
    int z = bx / 12, bt = bx % 12;
    const float* __restrict__ IN = (z == 0) ? Wq : (z == 1) ? Wk : (z == 2) ? Wv : Wo;
    int inStride  = (z < 3) ? HD : DIM;
    int outStride = (z < 3) ? DIM : HD;
    int rbase = (z < 3) ? 0 : bt * 64;
    int cbase = (z < 3) ? bt * 64 : 0;
    ushort* __restrict__ OUT = (z < 3) ? (Wt + (size_t)z * HD * DIM) : Wot;
    int t = threadIdx.x;
    int r = t >> 2, c0 = (t & 3) * 16;
    #pragma unroll
    for (int cc = 0; cc < 16; cc += 4) {
        float4 a = *(const float4*)&IN[(size_t)(rbase + r) * inStride + cbase + c0 + cc];
        tile[r][c0 + cc] = a.x; tile[r][c0 + cc + 1] = a.y;
        tile[r][c0 + cc + 2] = a.z; tile[r][c0 + cc + 3] = a.w;
    }
    __syncthreads();
    int cl = t >> 2, r0 = (t & 3) * 16;
    ushort tmp[16] __attribute__((aligned(16)));
    #pragma unroll
    for (int rr = 0; rr < 16; ++rr) tmp[rr] = f2b(tile[r0 + rr][cl]);
    *(float4*)&OUT[(size_t)(cbase + cl) * outStride + rbase + r0] = *(const float4*)tmp;
    *(float4*)&OUT[(size_t)(cbase + cl) * outStride + rbase + r0 + 8] = *(const float4*)&tmp[8];
}

// ---------------- Kernel 1: Q/K/V = x @ W (MFMA; x read as fp32) -----------
// grid (128 row-tiles, 6 col-groups), 256 thr = 4 waves; wave owns 16 rows,
// loops 6 col-tiles. NEW: register prefetch double-buffer — cc+1's 8
// B-fragments are loaded before cc's MFMAs/stores, hiding L2 latency under
// compute (the latency chain was the ~65us bottleneck). Numerics identical.
__global__ __launch_bounds__(256) void qkv_kernel(
    const float* __restrict__ x, const ushort* __restrict__ Wt,
    ushort* __restrict__ Q, ushort* __restrict__ K, ushort* __restrict__ V)
{
    int rt = blockIdx.x, yg = blockIdx.y;
    int t = threadIdx.x, w = t >> 6, lane = t & 63;
    int ln = lane & 15, q = lane >> 4;
    int m0 = rt * 64 + w * 16;

    // A-frags from fp32 x, converted in-reg (once per wave)
    float4 xa = *(const float4*)&x[(size_t)(m0 + ln) * DIM + q * 8];
    float4 xb_ = *(const float4*)&x[(size_t)(m0 + ln) * DIM + q * 8 + 4];
    float4 xc = *(const float4*)&x[(size_t)(m0 + ln) * DIM + 32 + q * 8];
    float4 xd = *(const float4*)&x[(size_t)(m0 + ln) * DIM + 32 + q * 8 + 4];
    ushort ta[8] __attribute__((aligned(16)));
    ushort tb[8] __attribute__((aligned(16)));
    ta[0]=f2b(xa.x); ta[1]=f2b(xa.y); ta[2]=f2b(xa.z); ta[3]=f2b(xa.w);
    ta[4]=f2b(xb_.x); ta[5]=f2b(xb_.y); ta[6]=f2b(xb_.z); ta[7]=f2b(xb_.w);
    tb[0]=f2b(xc.x); tb[1]=f2b(xc.y); tb[2]=f2b(xc.z); tb[3]=f2b(xc.w);
    tb[4]=f2b(xd.x); tb[5]=f2b(xd.y); tb[6]=f2b(xd.z); tb[7]=f2b(xd.w);
    bf16x8 af0 = *(const bf16x8*)ta;
    bf16x8 af1 = *(const bf16x8*)tb;

    // prefetch cc=0's B-fragments
    bf16x8 bf[8];
    {
        int ct0 = yg * 6;
        const ushort* __restrict__ Wz0 = Wt + (size_t)(ct0 / 12) * HD * DIM;
        int c0 = (ct0 % 12) * 64;
        #pragma unroll
        for (int nt = 0; nt < 4; ++nt) {
            int n = c0 + nt * 16 + ln;
            bf[2 * nt]     = *(const bf16x8*)&Wz0[(size_t)n * DIM + q * 8];
            bf[2 * nt + 1] = *(const bf16x8*)&Wz0[(size_t)n * DIM + 32 + q * 8];
        }
    }

    for (int cc = 0; cc < 6; ++cc) {
        int ct = yg * 6 + cc;
        int which = ct / 12;              // block-uniform (yg fixed)
        int col0 = (ct % 12) * 64;
        ushort* __restrict__ Y = (which == 0) ? Q : (which == 1) ? K : V;
        float sc = (which == 0) ? SCALE2 : 1.f;
        // consume current frags; issue next tile's loads FIRST
        bf16x8 cur[8];
        #pragma unroll
        for (int i = 0; i < 8; ++i) cur[i] = bf[i];
        if (cc < 5) {
            int ct2 = ct + 1;
            const ushort* __restrict__ Wz2 = Wt + (size_t)(ct2 / 12) * HD * DIM;
            int col2 = (ct2 % 12) * 64;
            #pragma unroll
            for (int nt = 0; nt < 4; ++nt) {
                int n = col2 + nt * 16 + ln;
                bf[2 * nt]     = *(const bf16x8*)&Wz2[(size_t)n * DIM + q * 8];
                bf[2 * nt + 1] = *(const bf16x8*)&Wz2[(size_t)n * DIM + 32 + q * 8];
            }
        }
        #pragma unroll
        for (int nt = 0; nt < 4; ++nt) {
            f32x4 acc = (f32x4){0.f, 0.f, 0.f, 0.f};
            acc = __builtin_amdgcn_mfma_f32_16x16x32_bf16(af0, cur[2 * nt], acc, 0, 0, 0);
            acc = __builtin_amdgcn_mfma_f32_16x16x32_bf16(af1, cur[2 * nt + 1], acc, 0, 0, 0);
            #pragma unroll
            for (int r = 0; r < 4; ++r)
                Y[(size_t)(m0 + q * 4 + r) * HD + col0 + nt * 16 + ln] = f2b(acc[r] * sc);
        }
    }
}

// ---------------- Kernel 1b: Vt[s][d][t] = V[s][t][d] ----------------------
// XOR-swizzled transposed scalar writes (banks spread), vector reads un-swizzle.
__global__ __launch_bounds__(256) void vtrans_kernel(
    const ushort* __restrict__ V, ushort* __restrict__ Vt)
{
    __shared__ ushort tileT[64 * LDT];
    int tt = blockIdx.x, s = blockIdx.y;
    const ushort* __restrict__ Vp = V + (size_t)s * SLICE;
    ushort* __restrict__ Vo = Vt + (size_t)s * SLICE;
    int t = threadIdx.x;
    int r = t >> 3, c = (t & 7) * 8;
    ushort va[8] __attribute__((aligned(16)));
    ushort vb[8] __attribute__((aligned(16)));
    *(float4*)va = *(const float4*)&Vp[(size_t)(tt * 64 + r) * DIM + c];
    *(float4*)vb = *(const float4*)&Vp[(size_t)(tt * 64 + r + 32) * DIM + c];
    int g0 = ((r >> 3) ^ (c >> 3)) * 8 + (r & 7);
    int g1 = (((r + 32) >> 3) ^ (c >> 3)) * 8 + (r & 7);
    #pragma unroll
    for (int k = 0; k < 8; ++k) {
        tileT[(c + k) * LDT + g0] = va[k];
        tileT[(c + k) * LDT + g1] = vb[k];
    }
    __syncthreads();
    #pragma unroll
    for (int j = 0; j < 2; ++j) {
        int flat = t + 256 * j;
        int d = flat >> 3, tg = flat & 7;
        int sg = tg ^ ((d >> 3) & 7);
        float4 vv = *(const float4*)&tileT[d * LDT + sg * 8];
        *(float4*)&Vo[(size_t)d * TSEQ + tt * 64 + tg * 8] = vv;
    }
}

// ---------------- Kernel 2: MFMA flash attention (32x32, reg-P, dbuf) ------
// r13 core + XCD-aware bijective swizzle ONLY (proven: FETCH 104->20MB).
// grid (16,48) -> bid; xcd=bid&7 owns 6 consecutive slices. Chain-break
// REVERTED (it put VALU adds on the softmax critical path, +6.5us).
__global__ __launch_bounds__(256, 3) void attn_kernel(
    const ushort* __restrict__ Qs, const ushort* __restrict__ Ks,
    const ushort* __restrict__ Vts, ushort* __restrict__ Zs)
{
    __shared__ ushort sh[4 * 64 * LDQ];   // [Qt0][Qt1][Vt0][Vt1]; epilogue reuses
    int bid = blockIdx.x + (blockIdx.y << 4);   // gridDim.x = 16
    int xcd = bid & 7, idx = bid >> 3;          // XCD = linear%8 (verified r13)
    int s = xcd * 6 + idx % 6;                  // bijective over [0,48)
    int itile = idx / 6;                        // [0,16)
    const ushort* __restrict__ Qp = Qs + (size_t)s * SLICE;
    const ushort* __restrict__ Kp = Ks + (size_t)s * SLICE;
    const ushort* __restrict__ Vp = Vts + (size_t)s * SLICE;   // [64][2048]
    ushort* __restrict__ Zp = Zs + (size_t)s * SLICE;
    int t = threadIdx.x, w = t >> 6, lane = t & 63;
    int i5 = lane & 31, hi = lane >> 5;

    // K fragments (B-operand): lane holds K[i0+i5][c*16 + hi*8 + e]
    bf16x8 kf[4];
    {
        size_t krow = (size_t)(itile * 128 + w * 32 + i5) * DIM;
        #pragma unroll
        for (int c = 0; c < 4; ++c)
            kf[c] = *(const bf16x8*)&Kp[krow + c * 16 + hi * 8];
    }

    f32x16 Of0, Of1;
    #pragma unroll
    for (int r = 0; r < 16; ++r) { Of0[r] = 0.f; Of1[r] = 0.f; }
    float lsum = 0.f;

    int sr = t >> 3, sc = (t & 7) * 8;
    const ushort* qsrc0 = &Qp[(size_t)sr * DIM + sc];
    const ushort* qsrc1 = &Qp[(size_t)(sr + 32) * DIM + sc];
    const ushort* vsrc0 = &Vp[(size_t)sr * TSEQ + sc];
    const ushort* vsrc1 = &Vp[(size_t)(sr + 32) * TSEQ + sc];

    // prologue: tile 0 -> buf 0, prefetch tile 1 into regs
    float4 qa0 = *(const float4*)qsrc0;
    float4 qa1 = *(const float4*)qsrc1;
    float4 va0 = *(const float4*)vsrc0;
    float4 va1 = *(const float4*)vsrc1;
    *(float4*)&sh[sr * LDQ + sc] = qa0;
    *(float4*)&sh[(sr + 32) * LDQ + sc] = qa1;
    *(float4*)&sh[2 * 64 * LDQ + sr * LDQ + sc] = va0;
    *(float4*)&sh[2 * 64 * LDQ + (sr + 32) * LDQ + sc] = va1;
    qa0 = *(const float4*)(qsrc0 + 64 * DIM);
    qa1 = *(const float4*)(qsrc1 + 64 * DIM);
    va0 = *(const float4*)(vsrc0 + 64);
    va1 = *(const float4*)(vsrc1 + 64);
    __syncthreads();

    for (int tt = 0; tt < 32; ++tt) {
        int ib = tt & 1;
        const ushort* Qc = sh + ib * (64 * LDQ);
        const ushort* Vc = sh + (2 + ib) * (64 * LDQ);
        // stage next tile into the other buffer; issue loads for tile tt+2
        if (tt < 31) {
            ushort* Qn = sh + (ib ^ 1) * (64 * LDQ);
            ushort* Vn = sh + (2 + (ib ^ 1)) * (64 * LDQ);
            *(float4*)&Qn[sr * LDQ + sc] = qa0;
            *(float4*)&Qn[(sr + 32) * LDQ + sc] = qa1;
            *(float4*)&Vn[sr * LDQ + sc] = va0;
            *(float4*)&Vn[(sr + 32) * LDQ + sc] = va1;
            if (tt < 30) {
                size_t qo = (size_t)(tt + 2) * 64 * DIM;
                int vo = (tt + 2) * 64;
                qa0 = *(const float4*)(qsrc0 + qo);
                qa1 = *(const float4*)(qsrc1 + qo);
                va0 = *(const float4*)(vsrc0 + vo);
                va1 = *(const float4*)(vsrc1 + vo);
            }
        }
        #pragma unroll
        for (int js = 0; js < 2; ++js) {
            // S^T (32j x 32i), Q pre-scaled: S already in log2-units
            f32x16 acc;
            #pragma unroll
            for (int r = 0; r < 16; ++r) acc[r] = 0.f;
            #pragma unroll
            for (int c = 0; c < 4; ++c) {
                bf16x8 aQ = *(const bf16x8*)&Qc[(js * 32 + i5) * LDQ + c * 16 + hi * 8];
                acc = __builtin_amdgcn_mfma_f32_32x32x16_bf16(aQ, kf[c], acc, 0, 0, 0);
            }
            // p = exp2(S); truncation-pack pairs (low short = even reg);
            // l summed from the truncated values (matches P exactly)
            unsigned wv[8];
            float ls = 0.f;
            #pragma unroll
            for (int k = 0; k < 8; ++k) {
                float p0 = __builtin_amdgcn_exp2f(acc[2 * k]);
                float p1 = __builtin_amdgcn_exp2f(acc[2 * k + 1]);
                unsigned int b0 = __float_as_uint(p0), b1 = __float_as_uint(p1);
                unsigned int t1 = b1 & 0xFFFF0000u;
                unsigned int h = (b0 >> 16) | t1;
                ls += __uint_as_float(h << 16) + __uint_as_float(t1);
                wv[k] = h;
            }
            lsum += ls;
            uint32x4 u0 = { wv[0], wv[1], wv[2], wv[3] };  // regs 0..7  -> j=(e&3)+8*(e>>2)+4hi
            uint32x4 u1 = { wv[4], wv[5], wv[6], wv[7] };  // regs 8..15 -> j=16+...
            bf16x8 pa0 = __builtin_bit_cast(bf16x8, u0);
            bf16x8 pa1 = __builtin_bit_cast(bf16x8, u1);
            // Z += P * V: B slot (hi,e) loads V^T row j matching pa's reg order
            #pragma unroll
            for (int dt = 0; dt < 2; ++dt) {
                int vbase = (dt * 32 + i5) * LDQ + js * 32 + 4 * hi;
                bf16x4 v0a = *(const bf16x4*)&Vc[vbase];
                bf16x4 v0b = *(const bf16x4*)&Vc[vbase + 8];
                bf16x4 v1a = *(const bf16x4*)&Vc[vbase + 16];
                bf16x4 v1b = *(const bf16x4*)&Vc[vbase + 24];
                bf16x8 vb0 = __builtin_shufflevector(v0a, v0b, 0, 1, 2, 3, 4, 5, 6, 7);
                bf16x8 vb1 = __builtin_shufflevector(v1a, v1b, 0, 1, 2, 3, 4, 5, 6, 7);
                if (dt == 0) {
                    Of0 = __builtin_amdgcn_mfma_f32_32x32x16_bf16(pa0, vb0, Of0, 0, 0, 0);
                    Of0 = __builtin_amdgcn_mfma_f32_32x32x16_bf16(pa1, vb1, Of0, 0, 0, 0);
                } else {
                    Of1 = __builtin_amdgcn_mfma_f32_32x32x16_bf16(pa0, vb0, Of1, 0, 0, 0);
                    Of1 = __builtin_amdgcn_mfma_f32_32x32x16_bf16(pa1, vb1, Of1, 0, 0, 0);
                }
            }
        }
        __syncthreads();
    }

    // l: partner lane (hi^1) holds the complementary j's for the same i=i5
    float l = lsum + __shfl_xor(lsum, 32);
    float linv = 1.f / l;
    // normalize + stage 128x64 output tile into LDS for coalesced writes
    #pragma unroll
    for (int r = 0; r < 16; ++r) {
        int cr = (r & 3) + 8 * (r >> 2);
        float li = __shfl(linv, cr + 4 * hi);
        int row = w * 32 + cr + 4 * hi;
        sh[row * LDQ + i5]      = f2b(Of0[r] * li);
        sh[row * LDQ + 32 + i5] = f2b(Of1[r] * li);
    }
    __syncthreads();
    int zr = t >> 1, zc = (t & 1) * 32;
    size_t zoff = (size_t)(itile * 128 + zr) * DIM + zc;
    #pragma unroll
    for (int c4 = 0; c4 < 4; ++c4)
        *(float4*)&Zp[zoff + c4 * 8] = *(const float4*)&sh[zr * LDQ + zc + c4 * 8];
}

// ---------------- Kernel 3: out = Z @ Wo (MFMA, fp32 out) ------------------
// M=8192, N=64, K=768. 256 one-wave blocks; 2 m-tiles per wave for ILP.
// (round-6 verbatim)
__global__ __launch_bounds__(64) void out_kernel(
    const ushort* __restrict__ Z, const ushort* __restrict__ Wot,
    float* __restrict__ out)
{
    int m0 = blockIdx.x * 32;
    int lane = threadIdx.x;
    int ln = lane & 15, q = lane >> 4;
    f32x4 acc[2][4];
    #pragma unroll
    for (int u = 0; u < 2; ++u)
        #pragma unroll
        for (int nt = 0; nt < 4; ++nt) acc[u][nt] = (f32x4){0.f, 0.f, 0.f, 0.f};
    for (int kc = 0; kc < 24; ++kc) {
        bf16x8 a0 = *(const bf16x8*)&Z[(size_t)(m0 + ln) * HD + kc * 32 + q * 8];
        bf16x8 a1 = *(const bf16x8*)&Z[(size_t)(m0 + 16 + ln) * HD + kc * 32 + q * 8];
        #pragma unroll
        for (int nt = 0; nt < 4; ++nt) {
            bf16x8 bf = *(const bf16x8*)&Wot[(size_t)(nt * 16 + ln) * HD + kc * 32 + q * 8];
            acc[0][nt] = __builtin_amdgcn_mfma_f32_16x16x32_bf16(a0, bf, acc[0][nt], 0, 0, 0);
            acc[1][nt] = __builtin_amdgcn_mfma_f32_16x16x32_bf16(a1, bf, acc[1][nt], 0, 0, 0);
        }
    }
    #pragma unroll
    for (int u = 0; u < 2; ++u)
        #pragma unroll
        for (int nt = 0; nt < 4; ++nt)
            #pragma unroll
            for (int r = 0; r < 4; ++r)
                out[(size_t)(m0 + u * 16 + q * 4 + r) * DIM + nt * 16 + ln] = acc[u][nt][r];
}

extern "C" void kernel_launch(void* const* d_in, const int* in_sizes, int n_in,
                              void* d_out, int out_size, void* d_ws, size_t ws_size,
                              hipStream_t stream)
{
    const float* x  = (const float*)d_in[0];
    const float* Wq = (const float*)d_in[1];
    const float* Wk = (const float*)d_in[2];
    const float* Wv = (const float*)d_in[3];
    const float* Wo = (const float*)d_in[4];
    float* out = (float*)d_out;

    const size_t n = (size_t)BT * HD;            // 6,291,456
    ushort* Q   = (ushort*)d_ws;
    ushort* K   = Q + n;
    ushort* V   = K + n;                         // Z aliases V (V dead after vtrans)
    ushort* Vt  = V + n;
    ushort* Wt  = Vt;                            // Wt lives only until qkv done;
    ushort* Wot = Vt + n;                        //   then vtrans overwrites with Vt
    ushort* Z   = V;

    prep_w<<<48, 256, 0, stream>>>(Wq, Wk, Wv, Wo, Wt, Wot);
    qkv_kernel<<<dim3(128, 6), 256, 0, stream>>>(x, Wt, Q, K, V);
    vtrans_kernel<<<dim3(32, 48), 256, 0, stream>>>(V, Vt);
    attn_kernel<<<dim3(16, 48), 256, 0, stream>>>(Q, K, Vt, Z);
    out_kernel<<<256, 64, 0, stream>>>(Z, Wot, out);
}